// Round 10
// baseline (89.713 us; speedup 1.0000x reference)
//
#include <hip/hip_runtime.h>
#include <hip/hip_bf16.h>
#include <math.h>

using bf16x8 = __attribute__((ext_vector_type(8))) __bf16;
using bf16x4 = __attribute__((ext_vector_type(4))) __bf16;
using f32x4  = __attribute__((ext_vector_type(4))) float;
using f32x16 = __attribute__((ext_vector_type(16))) float;

static constexpr int SEQ = 4096;
static constexpr int DIM = 64;
static constexpr int NB  = 4;
// 0.125 (1/sqrt(64)) * log2(e): scores in log2 domain -> exp2 everywhere
static constexpr float QSCALE = 0.18033688011112042f;

__device__ __forceinline__ void gload16(const void* g, void* l) {
    __builtin_amdgcn_global_load_lds(
        (const __attribute__((address_space(1))) unsigned int*)g,
        (__attribute__((address_space(3))) unsigned int*)l,
        16, 0, 0);
}

__device__ __forceinline__ float fast_exp2(float x) {
#if __has_builtin(__builtin_amdgcn_exp2f)
    return __builtin_amdgcn_exp2f(x);
#else
    return exp2f(x);
#endif
}

// ---------------------------------------------------------------------------
// Kernel 0: constants — pos-embed table peb[spos][c] = sin(spos*invf(c)) and
// W cast+transpose WT[slot][out][d]. One kernel, grid = SEQ*DIM/256.
// ---------------------------------------------------------------------------
__global__ __launch_bounds__(256)
void const_prep_kernel(const float* __restrict__ w, __bf16* __restrict__ WT,
                       float* __restrict__ peb)
{
    const int idx = (int)blockIdx.x * 256 + (int)threadIdx.x;  // < SEQ*DIM
    const int spos = idx >> 6;
    const int c    = idx & 63;
    const float invf = exp2f(-13.287712379549449f * ((float)c * 0.03125f));
    peb[idx] = __sinf((float)spos * invf);
    if (idx < 3 * DIM * DIM) {
        const int s = idx >> 12;
        const int o = (idx >> 6) & 63;
        const int d = idx & 63;
        WT[idx] = (__bf16)w[(s * DIM + d) * DIM + o];
    }
}

// ---------------------------------------------------------------------------
// Kernel 1: fused pos-embed + QKV projection (verified, unchanged math).
// Q pre-scaled by QSCALE (log2 domain), row-major. K row-major.
// V written FRAGMENT-MAJOR:
//   frag (kc, ks, dt) lane l elem e = V[kc*32 + ks*16 + (e&3)+8*(e>>2)+4*(l>>5)]
//                                      [dt*32 + (l&31)]
// (serves as PV A-operand: A lane l = V^T-row d=dt*32+l31, slots (hi,e) -> k.)
// ---------------------------------------------------------------------------
__global__ __launch_bounds__(256)
void qkv_prep_kernel(const float* __restrict__ x, const __bf16* __restrict__ WT,
                     const float* __restrict__ peb,
                     __bf16* __restrict__ Qb, __bf16* __restrict__ Kb,
                     __bf16* __restrict__ Vf)
{
    const int tid  = (int)threadIdx.x;
    const int lane = tid & 63;
    const int g  = lane >> 4;
    const int cl = lane & 15;
    const int rowbase = (int)blockIdx.x * 64 + (tid >> 6) * 16;  // in [0, B*S)

    const int row  = rowbase + cl;
    const int spos = row & (SEQ - 1);
    bf16x8 xa[2];
#pragma unroll
    for (int h = 0; h < 2; ++h) {
        const float* xp = x + (long)row * DIM + 32*h + 8*g;
        const float* pp = peb + (long)spos * DIM + 32*h + 8*g;
        f32x4 x0 = *reinterpret_cast<const f32x4*>(xp);
        f32x4 x1 = *reinterpret_cast<const f32x4*>(xp + 4);
        f32x4 p0 = *reinterpret_cast<const f32x4*>(pp);
        f32x4 p1 = *reinterpret_cast<const f32x4*>(pp + 4);
        bf16x8 v;
#pragma unroll
        for (int e = 0; e < 8; ++e) {
            const float xv = (e < 4) ? x0[e] : x1[e - 4];
            const float pe = (e < 4) ? p0[e] : p1[e - 4];
            v[e] = (__bf16)(xv + pe);
        }
        xa[h] = v;
    }

#pragma unroll
    for (int slot = 0; slot < 3; ++slot) {
        const __bf16* wt = WT + slot * DIM * DIM;
        f32x4 acc[4];
#pragma unroll
        for (int nt = 0; nt < 4; ++nt) acc[nt] = (f32x4){0.f, 0.f, 0.f, 0.f};
#pragma unroll
        for (int nt = 0; nt < 4; ++nt) {
            bf16x8 w0 = *reinterpret_cast<const bf16x8*>(wt + (nt*16 + cl) * DIM + 8*g);
            bf16x8 w1 = *reinterpret_cast<const bf16x8*>(wt + (nt*16 + cl) * DIM + 32 + 8*g);
            acc[nt] = __builtin_amdgcn_mfma_f32_16x16x32_bf16(xa[0], w0, acc[nt], 0, 0, 0);
            acc[nt] = __builtin_amdgcn_mfma_f32_16x16x32_bf16(xa[1], w1, acc[nt], 0, 0, 0);
        }

        // C/D layout (HW-verified): lane l, reg r -> row (l>>4)*4+r, col l&15.
        if (slot < 2) {
            __bf16* dst = (slot == 0) ? Qb : Kb;
            const float scale = (slot == 0) ? QSCALE : 1.0f;
#pragma unroll
            for (int nt = 0; nt < 4; ++nt)
#pragma unroll
                for (int r = 0; r < 4; ++r) {
                    const int ro = rowbase + 4*g + r;
                    dst[(long)ro * DIM + nt*16 + cl] = (__bf16)(acc[nt][r] * scale);
                }
        } else {
            const int bi = rowbase >> 12;
            const int sp = rowbase & (SEQ - 1);
            const int kc = sp >> 5;
            const int ks = (sp >> 4) & 1;
            const int lde = (32*(g&1) + cl)*8 + (g>>1)*4;   // + 128 for nt&1
            __bf16* vb = Vf + (((long)bi*128 + kc)*4 + ks*2)*512;
#pragma unroll
            for (int nt = 0; nt < 4; ++nt) {
                bf16x4 pk;
#pragma unroll
                for (int r = 0; r < 4; ++r) pk[r] = (__bf16)acc[nt][r];
                *reinterpret_cast<bf16x4*>(vb + (nt>>1)*512 + (nt&1)*128 + lde) = pk;
            }
        }
    }
}

// ---------------------------------------------------------------------------
// Kernel 2: flash attention, TRANSPOSED PV (O^T = V^T P^T) -> fully in-lane
// softmax. 8 independent waves/block (512 thr), same 32 q-rows, wave w owns
// k in [w*512, +512), 16 iters x 32 k, BARRIER-FREE main loop (wave-private
// K staging dbuf + counted vmcnt(8); V frags via coalesced reg loads).
// QK (swapped, mfma(K,Q)): lane l holds s[r] = S[q=l31][k=(r&3)+8(r>>2)+4hi].
// PV: acc[dt] = mfma(vf[ks*2+dt], pb[ks], acc[dt]) -> lane l holds
// O[q=l31][d=dt*32+(r&3)+8(r>>2)+4hi]: rescale/stats/normalize all in-lane.
// End: 8-way merge via LDS (2 barriers), 512-thread cooperative combine.
// grid = 512 (2 blocks/CU = 16 waves/CU), XCD-batch swizzle b=f(bid&7).
// ---------------------------------------------------------------------------
__global__ __launch_bounds__(512, 4)
void attn_kernel(const __bf16* __restrict__ Qb, const __bf16* __restrict__ Kb,
                 const __bf16* __restrict__ Vf, float* __restrict__ out)
{
    __shared__ char smem[71680];   // 64KB staging (8w x 2 x 4KB) / merge alias

    const int tid  = (int)threadIdx.x;
    const int w    = tid >> 6;
    const int lane = tid & 63;
    const int hi   = lane >> 5;
    const int l31  = lane & 31;

    const int bid = (int)blockIdx.x;
    const int x8  = bid & 7;
    const int b   = x8 & 3;
    const int qt  = ((x8 >> 2) << 6) | (bid >> 3);   // [0,128), bijective
    const int qbase = qt * 32;

    const __bf16* Qp  = Qb + ((long)b * SEQ + qbase) * DIM;
    const __bf16* Kpw = Kb + ((long)b * SEQ + w * 512) * DIM;
    const __bf16* Vfp = Vf + (((long)b * 128 + w * 16) * 4) * 512;

    // Q fragments (once): lane l31 row, d = d4*16 + 8*hi + e
    bf16x8 qf[4];
#pragma unroll
    for (int d4 = 0; d4 < 4; ++d4)
        qf[d4] = *reinterpret_cast<const bf16x8*>(Qp + l31*DIM + d4*16 + 8*hi);

    // K staging (wave-private): linear LDS dest, inverse-XOR-swizzled source
    char* kbase = smem + w * 8192;
    const int srow = lane >> 3;                 // 0..7
    const int ssw  = ((lane & 7) ^ srow) * 8;   // source chunk elems
    int rdo[4];
#pragma unroll
    for (int d4 = 0; d4 < 4; ++d4)
        rdo[d4] = l31*128 + (((2*d4 + hi) ^ (l31 & 7)) * 16);

    f32x16 acc[2];
#pragma unroll
    for (int dt = 0; dt < 2; ++dt)
#pragma unroll
        for (int r = 0; r < 16; ++r) acc[dt][r] = 0.f;
    float mrun = -INFINITY;
    float lsum = 0.f;

    // prologue: stage K(0), load V(0) frags
    bf16x8 vcur[4], vnxt[4];
#pragma unroll
    for (int j = 0; j < 4; ++j)
        gload16(Kpw + (long)(j*8 + srow) * DIM + ssw, kbase + j*1024 + lane*16);
#pragma unroll
    for (int f = 0; f < 4; ++f)
        vcur[f] = *reinterpret_cast<const bf16x8*>(Vfp + f*512 + lane*8);

#pragma unroll 2
    for (int n = 0; n < 16; ++n) {
        // ---- issue next-iter loads; counted wait for PREVIOUS iter's 8 ----
        if (n < 15) {
            const __bf16* kp = Kpw + (long)((n + 1) * 32) * DIM;
            char* kdst = kbase + ((n & 1) ^ 1) * 4096;
#pragma unroll
            for (int j = 0; j < 4; ++j)
                gload16(kp + (long)(j*8 + srow) * DIM + ssw, kdst + j*1024 + lane*16);
            const __bf16* vp = Vfp + (long)(n + 1) * 2048;
#pragma unroll
            for (int f = 0; f < 4; ++f)
                vnxt[f] = *reinterpret_cast<const bf16x8*>(vp + f*512 + lane*8);
            asm volatile("s_waitcnt vmcnt(8)" ::: "memory");
        } else {
            asm volatile("s_waitcnt vmcnt(0)" ::: "memory");
        }
        __builtin_amdgcn_sched_barrier(0);

        // ---- QK^T: one 32x32 tile, d=64 -> 4 MFMA ----
        const char* kb = kbase + (n & 1) * 4096;
        bf16x8 kf0 = *reinterpret_cast<const bf16x8*>(kb + rdo[0]);
        bf16x8 kf1 = *reinterpret_cast<const bf16x8*>(kb + rdo[1]);
        bf16x8 kf2 = *reinterpret_cast<const bf16x8*>(kb + rdo[2]);
        bf16x8 kf3 = *reinterpret_cast<const bf16x8*>(kb + rdo[3]);
        f32x16 s;
#pragma unroll
        for (int r = 0; r < 16; ++r) s[r] = 0.f;
        __builtin_amdgcn_s_setprio(1);
        s = __builtin_amdgcn_mfma_f32_32x32x16_bf16(kf0, qf[0], s, 0, 0, 0);
        s = __builtin_amdgcn_mfma_f32_32x32x16_bf16(kf1, qf[1], s, 0, 0, 0);
        s = __builtin_amdgcn_mfma_f32_32x32x16_bf16(kf2, qf[2], s, 0, 0, 0);
        s = __builtin_amdgcn_mfma_f32_32x32x16_bf16(kf3, qf[3], s, 0, 0, 0);
        __builtin_amdgcn_s_setprio(0);
        // s[r] = score_log2(q=l31, k = n*32 + (r&3)+8*(r>>2)+4*hi)

        // ---- online softmax (log2 domain), in-lane for q=l31 ----
        float tmax = fmaxf(fmaxf(s[0], s[1]), fmaxf(s[2], s[3]));
        tmax = fmaxf(tmax, fmaxf(fmaxf(s[4], s[5]), fmaxf(s[6], s[7])));
        tmax = fmaxf(tmax, fmaxf(fmaxf(s[8], s[9]), fmaxf(s[10], s[11])));
        tmax = fmaxf(tmax, fmaxf(fmaxf(s[12], s[13]), fmaxf(s[14], s[15])));
        tmax = fmaxf(tmax, __shfl_xor(tmax, 32));

        if (!__all(tmax <= mrun)) {
            const float mnew = fmaxf(mrun, tmax);
            const float corr = fast_exp2(mrun - mnew);   // first iter: 0
            lsum *= corr;
#pragma unroll
            for (int r = 0; r < 16; ++r) {   // IN-LANE: acc cols are q=l31
                acc[0][r] *= corr;
                acc[1][r] *= corr;
            }
            mrun = mnew;
        }

#pragma unroll
        for (int r = 0; r < 16; ++r) {
            const float p = fast_exp2(s[r] - mrun);
            s[r] = p;
            lsum += p;
        }

        // ---- P pack (B-operand): pb[ks] slot (hi,e) -> k = ks*16 + map ----
        bf16x8 pb0, pb1;
#pragma unroll
        for (int e = 0; e < 8; ++e) { pb0[e] = (__bf16)s[e]; pb1[e] = (__bf16)s[8 + e]; }

        // ---- PV transposed: acc[dt] = mfma(V^T frag, P frag) ----
        __builtin_amdgcn_s_setprio(1);
        acc[0] = __builtin_amdgcn_mfma_f32_32x32x16_bf16(vcur[0], pb0, acc[0], 0, 0, 0);
        acc[1] = __builtin_amdgcn_mfma_f32_32x32x16_bf16(vcur[1], pb0, acc[1], 0, 0, 0);
        acc[0] = __builtin_amdgcn_mfma_f32_32x32x16_bf16(vcur[2], pb1, acc[0], 0, 0, 0);
        acc[1] = __builtin_amdgcn_mfma_f32_32x32x16_bf16(vcur[3], pb1, acc[1], 0, 0, 0);
        __builtin_amdgcn_s_setprio(0);

#pragma unroll
        for (int f = 0; f < 4; ++f) vcur[f] = vnxt[f];
    }

    // full row-sum (merge hi halves; both halves then hold the same value)
    lsum += __shfl_xor(lsum, 32);

    // ---- 8-way k-merge through LDS (only sync points in the kernel) ----
    __syncthreads();   // staging dead; alias merge arrays
    float* lpart = (float*)smem;                 // [8][32][68] f32 (+4 pad)
    float* lm    = (float*)(smem + 69632);       // [8][32]
    float* ll    = (float*)(smem + 70656);       // [8][32]

    {
        float* lw = lpart + ((long)w*32 + l31) * 68;
#pragma unroll
        for (int dt = 0; dt < 2; ++dt)
#pragma unroll
            for (int j = 0; j < 4; ++j) {
                f32x4 v;
#pragma unroll
                for (int c = 0; c < 4; ++c) v[c] = acc[dt][4*j + c];
                *reinterpret_cast<f32x4*>(lw + dt*32 + 8*j + 4*hi) = v;
            }
        if (lane < 32) { lm[w*32 + l31] = mrun; ll[w*32 + l31] = lsum; }
    }
    __syncthreads();

    // cooperative combine: thread t -> q = t>>4, d-quad = (t&15)*4
    {
        const int q  = tid >> 4;
        const int dq = (tid & 15) * 4;
        float M = lm[q];
#pragma unroll
        for (int w2 = 1; w2 < 8; ++w2) M = fmaxf(M, lm[w2*32 + q]);
        float L = 0.f;
        f32x4 o = (f32x4){0.f, 0.f, 0.f, 0.f};
#pragma unroll
        for (int w2 = 0; w2 < 8; ++w2) {
            const float f = fast_exp2(lm[w2*32 + q] - M);
            L += ll[w2*32 + q] * f;
            f32x4 v = *reinterpret_cast<const f32x4*>(lpart + ((long)w2*32 + q)*68 + dq);
#pragma unroll
            for (int c = 0; c < 4; ++c) o[c] += v[c] * f;
        }
        const float inv = 1.f / L;
#pragma unroll
        for (int c = 0; c < 4; ++c) o[c] *= inv;
        *reinterpret_cast<f32x4*>(out + ((long)b * SEQ + qbase + q) * DIM + dq) = o;
    }
}

// ---------------------------------------------------------------------------
extern "C" void kernel_launch(void* const* d_in, const int* in_sizes, int n_in,
                              void* d_out, int out_size, void* d_ws, size_t ws_size,
                              hipStream_t stream)
{
    const float* x = (const float*)d_in[0];
    const float* w = (const float*)d_in[1];
    float* out = (float*)d_out;

    char* ws = (char*)d_ws;
    const size_t sz = (size_t)NB * SEQ * DIM * sizeof(__bf16);  // 2 MiB each
    __bf16* Qb  = (__bf16*)(ws);
    __bf16* Kb  = (__bf16*)(ws + sz);
    __bf16* Vf  = (__bf16*)(ws + 2 * sz);               // frag-major V, 2 MiB
    __bf16* WT  = (__bf16*)(ws + 3 * sz);               // 24 KiB
    float*  peb = (float*)(ws + 3 * sz + 32 * 1024);    // 1 MiB

    const_prep_kernel<<<SEQ * DIM / 256, 256, 0, stream>>>(w, WT, peb);

    qkv_prep_kernel<<<NB * SEQ / 64, 256, 0, stream>>>(x, WT, peb, Qb, Kb, Vf);

    attn_kernel<<<NB * SEQ / 32, 512, 0, stream>>>(Qb, Kb, Vf, out);
}

// Round 11
// 52.665 us; speedup vs baseline: 1.7035x; 1.7035x over previous
//
#include <hip/hip_runtime.h>
#include <hip/hip_bf16.h>
#include <math.h>

using bf16x8 = __attribute__((ext_vector_type(8))) __bf16;
using bf16x4 = __attribute__((ext_vector_type(4))) __bf16;
using f32x4  = __attribute__((ext_vector_type(4))) float;
using f32x16 = __attribute__((ext_vector_type(16))) float;

static constexpr int SEQ = 4096;
static constexpr int DIM = 64;
static constexpr int NB  = 4;
// 0.125 (1/sqrt(64)) * log2(e): scores in log2 domain -> exp2 everywhere
static constexpr float QSCALE = 0.18033688011112042f;

__device__ __forceinline__ void gload16(const void* g, void* l) {
    __builtin_amdgcn_global_load_lds(
        (const __attribute__((address_space(1))) unsigned int*)g,
        (__attribute__((address_space(3))) unsigned int*)l,
        16, 0, 0);
}

__device__ __forceinline__ float fast_exp2(float x) {
#if __has_builtin(__builtin_amdgcn_exp2f)
    return __builtin_amdgcn_exp2f(x);
#else
    return exp2f(x);
#endif
}

// ---------------------------------------------------------------------------
// Kernel 0: constants — pos-embed table peb[spos][c] = sin(spos*invf(c)) and
// W cast+transpose WT[slot][out][d]. One kernel, grid = SEQ*DIM/256.
// ---------------------------------------------------------------------------
__global__ __launch_bounds__(256)
void const_prep_kernel(const float* __restrict__ w, __bf16* __restrict__ WT,
                       float* __restrict__ peb)
{
    const int idx = (int)blockIdx.x * 256 + (int)threadIdx.x;  // < SEQ*DIM
    const int spos = idx >> 6;
    const int c    = idx & 63;
    const float invf = exp2f(-13.287712379549449f * ((float)c * 0.03125f));
    peb[idx] = __sinf((float)spos * invf);
    if (idx < 3 * DIM * DIM) {
        const int s = idx >> 12;
        const int o = (idx >> 6) & 63;
        const int d = idx & 63;
        WT[idx] = (__bf16)w[(s * DIM + d) * DIM + o];
    }
}

// ---------------------------------------------------------------------------
// Kernel 1: fused pos-embed + QKV projection (verified, unchanged math).
// Q pre-scaled by QSCALE (log2 domain), row-major. K row-major.
// V written FRAGMENT-MAJOR:
//   frag (kc, ks, dt) lane l elem e = V[kc*32 + ks*16 + (e&3)+8*(e>>2)+4*(l>>5)]
//                                      [dt*32 + (l&31)]
// (serves as PV A-operand: A lane l = V^T-row d=dt*32+l31, slots (hi,e) -> k.)
// ---------------------------------------------------------------------------
__global__ __launch_bounds__(256)
void qkv_prep_kernel(const float* __restrict__ x, const __bf16* __restrict__ WT,
                     const float* __restrict__ peb,
                     __bf16* __restrict__ Qb, __bf16* __restrict__ Kb,
                     __bf16* __restrict__ Vf)
{
    const int tid  = (int)threadIdx.x;
    const int lane = tid & 63;
    const int g  = lane >> 4;
    const int cl = lane & 15;
    const int rowbase = (int)blockIdx.x * 64 + (tid >> 6) * 16;  // in [0, B*S)

    const int row  = rowbase + cl;
    const int spos = row & (SEQ - 1);
    bf16x8 xa[2];
#pragma unroll
    for (int h = 0; h < 2; ++h) {
        const float* xp = x + (long)row * DIM + 32*h + 8*g;
        const float* pp = peb + (long)spos * DIM + 32*h + 8*g;
        f32x4 x0 = *reinterpret_cast<const f32x4*>(xp);
        f32x4 x1 = *reinterpret_cast<const f32x4*>(xp + 4);
        f32x4 p0 = *reinterpret_cast<const f32x4*>(pp);
        f32x4 p1 = *reinterpret_cast<const f32x4*>(pp + 4);
        bf16x8 v;
#pragma unroll
        for (int e = 0; e < 8; ++e) {
            const float xv = (e < 4) ? x0[e] : x1[e - 4];
            const float pe = (e < 4) ? p0[e] : p1[e - 4];
            v[e] = (__bf16)(xv + pe);
        }
        xa[h] = v;
    }

#pragma unroll
    for (int slot = 0; slot < 3; ++slot) {
        const __bf16* wt = WT + slot * DIM * DIM;
        f32x4 acc[4];
#pragma unroll
        for (int nt = 0; nt < 4; ++nt) acc[nt] = (f32x4){0.f, 0.f, 0.f, 0.f};
#pragma unroll
        for (int nt = 0; nt < 4; ++nt) {
            bf16x8 w0 = *reinterpret_cast<const bf16x8*>(wt + (nt*16 + cl) * DIM + 8*g);
            bf16x8 w1 = *reinterpret_cast<const bf16x8*>(wt + (nt*16 + cl) * DIM + 32 + 8*g);
            acc[nt] = __builtin_amdgcn_mfma_f32_16x16x32_bf16(xa[0], w0, acc[nt], 0, 0, 0);
            acc[nt] = __builtin_amdgcn_mfma_f32_16x16x32_bf16(xa[1], w1, acc[nt], 0, 0, 0);
        }

        // C/D layout (HW-verified): lane l, reg r -> row (l>>4)*4+r, col l&15.
        if (slot < 2) {
            __bf16* dst = (slot == 0) ? Qb : Kb;
            const float scale = (slot == 0) ? QSCALE : 1.0f;
#pragma unroll
            for (int nt = 0; nt < 4; ++nt)
#pragma unroll
                for (int r = 0; r < 4; ++r) {
                    const int ro = rowbase + 4*g + r;
                    dst[(long)ro * DIM + nt*16 + cl] = (__bf16)(acc[nt][r] * scale);
                }
        } else {
            const int bi = rowbase >> 12;
            const int sp = rowbase & (SEQ - 1);
            const int kc = sp >> 5;
            const int ks = (sp >> 4) & 1;
            const int lde = (32*(g&1) + cl)*8 + (g>>1)*4;   // + 128 for nt&1
            __bf16* vb = Vf + (((long)bi*128 + kc)*4 + ks*2)*512;
#pragma unroll
            for (int nt = 0; nt < 4; ++nt) {
                bf16x4 pk;
#pragma unroll
                for (int r = 0; r < 4; ++r) pk[r] = (__bf16)acc[nt][r];
                *reinterpret_cast<bf16x4*>(vb + (nt>>1)*512 + (nt&1)*128 + lde) = pk;
            }
        }
    }
}

// ---------------------------------------------------------------------------
// Kernel 2: flash attention, TRANSPOSED PV (O^T = V^T P^T) -> fully in-lane
// softmax. 8 independent waves/block (512 thr), same 32 q-rows, wave w owns
// k in [w*512, +512), 16 iters x 32 k, BARRIER-FREE main loop (wave-private
// K staging dbuf + counted vmcnt(8); V frags via coalesced reg loads).
// QK (swapped, mfma(K,Q)): lane l holds s[r] = S[q=l31][k=(r&3)+8(r>>2)+4hi].
// PV: acc[dt] = mfma(vf[ks*2+dt], pb[ks], acc[dt]) -> lane l holds
// O[q=l31][d=dt*32+(r&3)+8(r>>2)+4hi]: rescale/stats/normalize all in-lane.
// End: 8-way merge via LDS (2 barriers), 512-thread cooperative combine.
// grid = 512 (2 blocks/CU = 16 waves/CU), XCD-batch swizzle b=f(bid&7).
// R10 fix: __launch_bounds__(512, 2) — R9's (512,4) capped VGPR at 64 and
// spilled every accumulator to scratch (FETCH 5.2->84 MB). Cap 128 >= ~110
// needed; 4 waves/SIMD still achievable (2 x 71.6KB LDS fits 160KB).
// ---------------------------------------------------------------------------
__global__ __launch_bounds__(512, 2)
void attn_kernel(const __bf16* __restrict__ Qb, const __bf16* __restrict__ Kb,
                 const __bf16* __restrict__ Vf, float* __restrict__ out)
{
    __shared__ char smem[71680];   // 64KB staging (8w x 2 x 4KB) / merge alias

    const int tid  = (int)threadIdx.x;
    const int w    = tid >> 6;
    const int lane = tid & 63;
    const int hi   = lane >> 5;
    const int l31  = lane & 31;

    const int bid = (int)blockIdx.x;
    const int x8  = bid & 7;
    const int b   = x8 & 3;
    const int qt  = ((x8 >> 2) << 6) | (bid >> 3);   // [0,128), bijective
    const int qbase = qt * 32;

    const __bf16* Qp  = Qb + ((long)b * SEQ + qbase) * DIM;
    const __bf16* Kpw = Kb + ((long)b * SEQ + w * 512) * DIM;
    const __bf16* Vfp = Vf + (((long)b * 128 + w * 16) * 4) * 512;

    // Q fragments (once): lane l31 row, d = d4*16 + 8*hi + e
    bf16x8 qf[4];
#pragma unroll
    for (int d4 = 0; d4 < 4; ++d4)
        qf[d4] = *reinterpret_cast<const bf16x8*>(Qp + l31*DIM + d4*16 + 8*hi);

    // K staging (wave-private): linear LDS dest, inverse-XOR-swizzled source
    char* kbase = smem + w * 8192;
    const int srow = lane >> 3;                 // 0..7
    const int ssw  = ((lane & 7) ^ srow) * 8;   // source chunk elems
    int rdo[4];
#pragma unroll
    for (int d4 = 0; d4 < 4; ++d4)
        rdo[d4] = l31*128 + (((2*d4 + hi) ^ (l31 & 7)) * 16);

    f32x16 acc[2];
#pragma unroll
    for (int dt = 0; dt < 2; ++dt)
#pragma unroll
        for (int r = 0; r < 16; ++r) acc[dt][r] = 0.f;
    float mrun = -INFINITY;
    float lsum = 0.f;

    // prologue: stage K(0), load V(0) frags
    bf16x8 vcur[4], vnxt[4];
#pragma unroll
    for (int j = 0; j < 4; ++j)
        gload16(Kpw + (long)(j*8 + srow) * DIM + ssw, kbase + j*1024 + lane*16);
#pragma unroll
    for (int f = 0; f < 4; ++f)
        vcur[f] = *reinterpret_cast<const bf16x8*>(Vfp + f*512 + lane*8);

#pragma unroll 2
    for (int n = 0; n < 16; ++n) {
        // ---- issue next-iter loads; counted wait for PREVIOUS iter's 8 ----
        if (n < 15) {
            const __bf16* kp = Kpw + (long)((n + 1) * 32) * DIM;
            char* kdst = kbase + ((n & 1) ^ 1) * 4096;
#pragma unroll
            for (int j = 0; j < 4; ++j)
                gload16(kp + (long)(j*8 + srow) * DIM + ssw, kdst + j*1024 + lane*16);
            const __bf16* vp = Vfp + (long)(n + 1) * 2048;
#pragma unroll
            for (int f = 0; f < 4; ++f)
                vnxt[f] = *reinterpret_cast<const bf16x8*>(vp + f*512 + lane*8);
            asm volatile("s_waitcnt vmcnt(8)" ::: "memory");
        } else {
            asm volatile("s_waitcnt vmcnt(0)" ::: "memory");
        }
        __builtin_amdgcn_sched_barrier(0);

        // ---- QK^T: one 32x32 tile, d=64 -> 4 MFMA ----
        const char* kb = kbase + (n & 1) * 4096;
        bf16x8 kf0 = *reinterpret_cast<const bf16x8*>(kb + rdo[0]);
        bf16x8 kf1 = *reinterpret_cast<const bf16x8*>(kb + rdo[1]);
        bf16x8 kf2 = *reinterpret_cast<const bf16x8*>(kb + rdo[2]);
        bf16x8 kf3 = *reinterpret_cast<const bf16x8*>(kb + rdo[3]);
        f32x16 s;
#pragma unroll
        for (int r = 0; r < 16; ++r) s[r] = 0.f;
        __builtin_amdgcn_s_setprio(1);
        s = __builtin_amdgcn_mfma_f32_32x32x16_bf16(kf0, qf[0], s, 0, 0, 0);
        s = __builtin_amdgcn_mfma_f32_32x32x16_bf16(kf1, qf[1], s, 0, 0, 0);
        s = __builtin_amdgcn_mfma_f32_32x32x16_bf16(kf2, qf[2], s, 0, 0, 0);
        s = __builtin_amdgcn_mfma_f32_32x32x16_bf16(kf3, qf[3], s, 0, 0, 0);
        __builtin_amdgcn_s_setprio(0);
        // s[r] = score_log2(q=l31, k = n*32 + (r&3)+8*(r>>2)+4*hi)

        // ---- online softmax (log2 domain), in-lane for q=l31 ----
        float tmax = fmaxf(fmaxf(s[0], s[1]), fmaxf(s[2], s[3]));
        tmax = fmaxf(tmax, fmaxf(fmaxf(s[4], s[5]), fmaxf(s[6], s[7])));
        tmax = fmaxf(tmax, fmaxf(fmaxf(s[8], s[9]), fmaxf(s[10], s[11])));
        tmax = fmaxf(tmax, fmaxf(fmaxf(s[12], s[13]), fmaxf(s[14], s[15])));
        tmax = fmaxf(tmax, __shfl_xor(tmax, 32));

        if (!__all(tmax <= mrun)) {
            const float mnew = fmaxf(mrun, tmax);
            const float corr = fast_exp2(mrun - mnew);   // first iter: 0
            lsum *= corr;
#pragma unroll
            for (int r = 0; r < 16; ++r) {   // IN-LANE: acc cols are q=l31
                acc[0][r] *= corr;
                acc[1][r] *= corr;
            }
            mrun = mnew;
        }

#pragma unroll
        for (int r = 0; r < 16; ++r) {
            const float p = fast_exp2(s[r] - mrun);
            s[r] = p;
            lsum += p;
        }

        // ---- P pack (B-operand): pb[ks] slot (hi,e) -> k = ks*16 + map ----
        bf16x8 pb0, pb1;
#pragma unroll
        for (int e = 0; e < 8; ++e) { pb0[e] = (__bf16)s[e]; pb1[e] = (__bf16)s[8 + e]; }

        // ---- PV transposed: acc[dt] = mfma(V^T frag, P frag) ----
        __builtin_amdgcn_s_setprio(1);
        acc[0] = __builtin_amdgcn_mfma_f32_32x32x16_bf16(vcur[0], pb0, acc[0], 0, 0, 0);
        acc[1] = __builtin_amdgcn_mfma_f32_32x32x16_bf16(vcur[1], pb0, acc[1], 0, 0, 0);
        acc[0] = __builtin_amdgcn_mfma_f32_32x32x16_bf16(vcur[2], pb1, acc[0], 0, 0, 0);
        acc[1] = __builtin_amdgcn_mfma_f32_32x32x16_bf16(vcur[3], pb1, acc[1], 0, 0, 0);
        __builtin_amdgcn_s_setprio(0);

#pragma unroll
        for (int f = 0; f < 4; ++f) vcur[f] = vnxt[f];
    }

    // full row-sum (merge hi halves; both halves then hold the same value)
    lsum += __shfl_xor(lsum, 32);

    // ---- 8-way k-merge through LDS (only sync points in the kernel) ----
    __syncthreads();   // staging dead; alias merge arrays
    float* lpart = (float*)smem;                 // [8][32][68] f32 (+4 pad)
    float* lm    = (float*)(smem + 69632);       // [8][32]
    float* ll    = (float*)(smem + 70656);       // [8][32]

    {
        float* lw = lpart + ((long)w*32 + l31) * 68;
#pragma unroll
        for (int dt = 0; dt < 2; ++dt)
#pragma unroll
            for (int j = 0; j < 4; ++j) {
                f32x4 v;
#pragma unroll
                for (int c = 0; c < 4; ++c) v[c] = acc[dt][4*j + c];
                *reinterpret_cast<f32x4*>(lw + dt*32 + 8*j + 4*hi) = v;
            }
        if (lane < 32) { lm[w*32 + l31] = mrun; ll[w*32 + l31] = lsum; }
    }
    __syncthreads();

    // cooperative combine: thread t -> q = t>>4, d-quad = (t&15)*4
    {
        const int q  = tid >> 4;
        const int dq = (tid & 15) * 4;
        float M = lm[q];
#pragma unroll
        for (int w2 = 1; w2 < 8; ++w2) M = fmaxf(M, lm[w2*32 + q]);
        float L = 0.f;
        f32x4 o = (f32x4){0.f, 0.f, 0.f, 0.f};
#pragma unroll
        for (int w2 = 0; w2 < 8; ++w2) {
            const float f = fast_exp2(lm[w2*32 + q] - M);
            L += ll[w2*32 + q] * f;
            f32x4 v = *reinterpret_cast<const f32x4*>(lpart + ((long)w2*32 + q)*68 + dq);
#pragma unroll
            for (int c = 0; c < 4; ++c) o[c] += v[c] * f;
        }
        const float inv = 1.f / L;
#pragma unroll
        for (int c = 0; c < 4; ++c) o[c] *= inv;
        *reinterpret_cast<f32x4*>(out + ((long)b * SEQ + qbase + q) * DIM + dq) = o;
    }
}

// ---------------------------------------------------------------------------
extern "C" void kernel_launch(void* const* d_in, const int* in_sizes, int n_in,
                              void* d_out, int out_size, void* d_ws, size_t ws_size,
                              hipStream_t stream)
{
    const float* x = (const float*)d_in[0];
    const float* w = (const float*)d_in[1];
    float* out = (float*)d_out;

    char* ws = (char*)d_ws;
    const size_t sz = (size_t)NB * SEQ * DIM * sizeof(__bf16);  // 2 MiB each
    __bf16* Qb  = (__bf16*)(ws);
    __bf16* Kb  = (__bf16*)(ws + sz);
    __bf16* Vf  = (__bf16*)(ws + 2 * sz);               // frag-major V, 2 MiB
    __bf16* WT  = (__bf16*)(ws + 3 * sz);               // 24 KiB
    float*  peb = (float*)(ws + 3 * sz + 32 * 1024);    // 1 MiB

    const_prep_kernel<<<SEQ * DIM / 256, 256, 0, stream>>>(w, WT, peb);

    qkv_prep_kernel<<<NB * SEQ / 64, 256, 0, stream>>>(x, WT, peb, Qb, Kb, Vf);

    attn_kernel<<<NB * SEQ / 32, 512, 0, stream>>>(Qb, Kb, Vf, out);
}

// Round 12
// 47.933 us; speedup vs baseline: 1.8716x; 1.0987x over previous
//
#include <hip/hip_runtime.h>
#include <hip/hip_bf16.h>
#include <math.h>

using bf16x8 = __attribute__((ext_vector_type(8))) __bf16;
using bf16x4 = __attribute__((ext_vector_type(4))) __bf16;
using f32x4  = __attribute__((ext_vector_type(4))) float;
using f32x16 = __attribute__((ext_vector_type(16))) float;

static constexpr int SEQ = 4096;
static constexpr int DIM = 64;
static constexpr int NB  = 4;
// 0.125 (1/sqrt(64)) * log2(e): scores in log2 domain -> exp2 everywhere
static constexpr float QSCALE = 0.18033688011112042f;

__device__ __forceinline__ float fast_exp2(float x) {
#if __has_builtin(__builtin_amdgcn_exp2f)
    return __builtin_amdgcn_exp2f(x);
#else
    return exp2f(x);
#endif
}

// ---------------------------------------------------------------------------
// Kernel 0: constants — pos-embed table peb[spos][c] = sin(spos*invf(c)) and
// W cast+transpose WT[slot][out][d].
// ---------------------------------------------------------------------------
__global__ __launch_bounds__(256)
void const_prep_kernel(const float* __restrict__ w, __bf16* __restrict__ WT,
                       float* __restrict__ peb)
{
    const int idx = (int)blockIdx.x * 256 + (int)threadIdx.x;  // < SEQ*DIM
    const int spos = idx >> 6;
    const int c    = idx & 63;
    const float invf = exp2f(-13.287712379549449f * ((float)c * 0.03125f));
    peb[idx] = __sinf((float)spos * invf);
    if (idx < 3 * DIM * DIM) {
        const int s = idx >> 12;
        const int o = (idx >> 6) & 63;
        const int d = idx & 63;
        WT[idx] = (__bf16)w[(s * DIM + d) * DIM + o];
    }
}

// ---------------------------------------------------------------------------
// Kernel 1: fused pos-embed + QKV projection. ALL outputs fragment-major.
//
// Q/K (slots 0,1): SWAPPED mfma(wf, xa) -> acc[nt][r] = OUT[s=rowbase+cl]
//   [o = nt*16+4g+r] (lane holds seq on cl, feature on regs). Frag layout
//   region (c32 = seq>>5, d4): lane l elem e = OUT[c32*32+(l&31)]
//   [d4*16 + 8*(l>>5) + e]. Dest lane = (sp&16)+cl+32*(g>>1),
//   elems 4*(g&1)+r contiguous -> bf16x4 stores, wave covers 512B runs.
// V (slot 2): normal mfma; frag (kc, ks, dt) lane l elem e =
//   V[kc*32 + ks*16 + (e&3)+8*(e>>2)+4*(l>>5)][dt*32 + (l&31)]  (PV sigma).
// Q pre-scaled by QSCALE (log2 domain).
// ---------------------------------------------------------------------------
__global__ __launch_bounds__(256)
void qkv_prep_kernel(const float* __restrict__ x, const __bf16* __restrict__ WT,
                     const float* __restrict__ peb,
                     __bf16* __restrict__ Qf, __bf16* __restrict__ Kf,
                     __bf16* __restrict__ Vf)
{
    const int tid  = (int)threadIdx.x;
    const int lane = tid & 63;
    const int g  = lane >> 4;
    const int cl = lane & 15;
    const int rowbase = (int)blockIdx.x * 64 + (tid >> 6) * 16;  // in [0, B*S)

    const int row  = rowbase + cl;
    const int spos = row & (SEQ - 1);
    bf16x8 xa[2];
#pragma unroll
    for (int h = 0; h < 2; ++h) {
        const float* xp = x + (long)row * DIM + 32*h + 8*g;
        const float* pp = peb + (long)spos * DIM + 32*h + 8*g;
        f32x4 x0 = *reinterpret_cast<const f32x4*>(xp);
        f32x4 x1 = *reinterpret_cast<const f32x4*>(xp + 4);
        f32x4 p0 = *reinterpret_cast<const f32x4*>(pp);
        f32x4 p1 = *reinterpret_cast<const f32x4*>(pp + 4);
        bf16x8 v;
#pragma unroll
        for (int e = 0; e < 8; ++e) {
            const float xv = (e < 4) ? x0[e] : x1[e - 4];
            const float pe = (e < 4) ? p0[e] : p1[e - 4];
            v[e] = (__bf16)(xv + pe);
        }
        xa[h] = v;
    }

    const int bi  = rowbase >> 12;
    const int sp  = rowbase & (SEQ - 1);
    const int c32 = sp >> 5;
    const int rb16 = sp & 16;

#pragma unroll
    for (int slot = 0; slot < 3; ++slot) {
        const __bf16* wt = WT + slot * DIM * DIM;
        f32x4 acc[4];
#pragma unroll
        for (int nt = 0; nt < 4; ++nt) acc[nt] = (f32x4){0.f, 0.f, 0.f, 0.f};
#pragma unroll
        for (int nt = 0; nt < 4; ++nt) {
            bf16x8 w0 = *reinterpret_cast<const bf16x8*>(wt + (nt*16 + cl) * DIM + 8*g);
            bf16x8 w1 = *reinterpret_cast<const bf16x8*>(wt + (nt*16 + cl) * DIM + 32 + 8*g);
            if (slot < 2) {   // swapped: lane -> seq, regs -> feature
                acc[nt] = __builtin_amdgcn_mfma_f32_16x16x32_bf16(w0, xa[0], acc[nt], 0, 0, 0);
                acc[nt] = __builtin_amdgcn_mfma_f32_16x16x32_bf16(w1, xa[1], acc[nt], 0, 0, 0);
            } else {          // normal: lane -> feature, regs -> seq
                acc[nt] = __builtin_amdgcn_mfma_f32_16x16x32_bf16(xa[0], w0, acc[nt], 0, 0, 0);
                acc[nt] = __builtin_amdgcn_mfma_f32_16x16x32_bf16(xa[1], w1, acc[nt], 0, 0, 0);
            }
        }

        if (slot < 2) {
            __bf16* dst = (slot == 0) ? Qf : Kf;
            const float scale = (slot == 0) ? QSCALE : 1.0f;
            // elem offset within region: lane*8 + first elem
            __bf16* base = dst + ((long)(bi*128 + c32) * 4) * 512
                         + (rb16 + cl + 32*(g >> 1)) * 8 + 4*(g & 1);
#pragma unroll
            for (int nt = 0; nt < 4; ++nt) {
                bf16x4 pk;
#pragma unroll
                for (int r = 0; r < 4; ++r) pk[r] = (__bf16)(acc[nt][r] * scale);
                *reinterpret_cast<bf16x4*>(base + nt*512) = pk;
            }
        } else {
            const int ks  = (sp >> 4) & 1;
            const int lde = (32*(g&1) + cl)*8 + (g>>1)*4;   // + 128 for nt&1
            __bf16* vb = Vf + (((long)bi*128 + c32)*4 + ks*2)*512;
#pragma unroll
            for (int nt = 0; nt < 4; ++nt) {
                bf16x4 pk;
#pragma unroll
                for (int r = 0; r < 4; ++r) pk[r] = (__bf16)acc[nt][r];
                *reinterpret_cast<bf16x4*>(vb + (nt>>1)*512 + (nt&1)*128 + lde) = pk;
            }
        }
    }
}

// ---------------------------------------------------------------------------
// Kernel 2: flash attention, ZERO-LDS main loop. 8 independent waves (512
// thr), same 32 q-rows, wave w owns k in [w*512,+512), 16 iters x 32 k.
// All operands fragment-major in L2: per iter 8 fully-coalesced 1KB reg
// loads (4 V this-iter + 4 K next-iter prefetch), 8 MFMA, in-lane softmax.
// No LDS/ds_read/barrier/asm in the loop — compiler manages counted vmcnt.
// QK: s = mfma(kf,qf) -> lane l holds S^T[k-pattern][q=l31]; PV transposed:
// acc[dt] = mfma(V^T frag, P frag) -> O^T cols q=l31: everything in-lane.
// Epilogue: cascade merge 8->4->2->1 through 35KB LDS (4 barriers), then
// cooperative coalesced f32x4 out store. grid = 512, XCD swizzle b=f(bid&7).
// ---------------------------------------------------------------------------
__global__ __launch_bounds__(512)
void attn_kernel(const __bf16* __restrict__ Qf, const __bf16* __restrict__ Kf,
                 const __bf16* __restrict__ Vf, float* __restrict__ out)
{
    __shared__ char smem[35840];   // lpart[4][32][68] f32 (34816) + lms/lls (512+512)
    float* lpart = (float*)smem;
    float* lms   = (float*)(smem + 34816);
    float* lls   = (float*)(smem + 35328);

    const int tid  = (int)threadIdx.x;
    const int w    = tid >> 6;
    const int lane = tid & 63;
    const int hi   = lane >> 5;
    const int l31  = lane & 31;

    const int bid = (int)blockIdx.x;
    const int x8  = bid & 7;
    const int b   = x8 & 3;
    const int qt  = ((x8 >> 2) << 6) | (bid >> 3);   // [0,128), bijective
    const int qbase = qt * 32;

    const __bf16* Qfp = Qf + ((long)(b*128 + qt)  * 4) * 512 + lane*8;
    const __bf16* Kfp = Kf + ((long)(b*128 + w*16) * 4) * 512 + lane*8;
    const __bf16* Vfp = Vf + ((long)(b*128 + w*16) * 4) * 512 + lane*8;

    // Q fragments (once, coalesced): elem (hi,e) -> d = d4*16 + 8hi + e
    bf16x8 qf[4];
#pragma unroll
    for (int d4 = 0; d4 < 4; ++d4)
        qf[d4] = *reinterpret_cast<const bf16x8*>(Qfp + d4*512);

    f32x16 acc[2];
#pragma unroll
    for (int dt = 0; dt < 2; ++dt)
#pragma unroll
        for (int r = 0; r < 16; ++r) acc[dt][r] = 0.f;
    float mrun = -INFINITY;
    float lsum = 0.f;

    // prologue: prefetch K(0)
    bf16x8 kcur[4], knxt[4], vcur[4];
#pragma unroll
    for (int d4 = 0; d4 < 4; ++d4)
        kcur[d4] = *reinterpret_cast<const bf16x8*>(Kfp + d4*512);

#pragma unroll 2
    for (int n = 0; n < 16; ++n) {
        // V(n) for this iter's PV (QK+softmax covers its latency) and
        // K(n+1) prefetch (full iteration of cover).
#pragma unroll
        for (int f = 0; f < 4; ++f)
            vcur[f] = *reinterpret_cast<const bf16x8*>(Vfp + n*2048 + f*512);
        if (n < 15) {
#pragma unroll
            for (int d4 = 0; d4 < 4; ++d4)
                knxt[d4] = *reinterpret_cast<const bf16x8*>(Kfp + (n + 1)*2048 + d4*512);
        }

        // ---- QK^T: one 32x32 tile, d=64 -> 4 MFMA ----
        f32x16 s;
#pragma unroll
        for (int r = 0; r < 16; ++r) s[r] = 0.f;
        __builtin_amdgcn_s_setprio(1);
        s = __builtin_amdgcn_mfma_f32_32x32x16_bf16(kcur[0], qf[0], s, 0, 0, 0);
        s = __builtin_amdgcn_mfma_f32_32x32x16_bf16(kcur[1], qf[1], s, 0, 0, 0);
        s = __builtin_amdgcn_mfma_f32_32x32x16_bf16(kcur[2], qf[2], s, 0, 0, 0);
        s = __builtin_amdgcn_mfma_f32_32x32x16_bf16(kcur[3], qf[3], s, 0, 0, 0);
        __builtin_amdgcn_s_setprio(0);
        // s[r] = score_log2(q=l31, k = n*32 + (r&3)+8*(r>>2)+4*hi)

        // ---- online softmax (log2 domain), in-lane for q=l31 ----
        float tmax = fmaxf(fmaxf(s[0], s[1]), fmaxf(s[2], s[3]));
        tmax = fmaxf(tmax, fmaxf(fmaxf(s[4], s[5]), fmaxf(s[6], s[7])));
        tmax = fmaxf(tmax, fmaxf(fmaxf(s[8], s[9]), fmaxf(s[10], s[11])));
        tmax = fmaxf(tmax, fmaxf(fmaxf(s[12], s[13]), fmaxf(s[14], s[15])));
        tmax = fmaxf(tmax, __shfl_xor(tmax, 32));

        if (!__all(tmax <= mrun)) {
            const float mnew = fmaxf(mrun, tmax);
            const float corr = fast_exp2(mrun - mnew);   // first iter: 0
            lsum *= corr;
#pragma unroll
            for (int r = 0; r < 16; ++r) {   // in-lane: acc cols are q=l31
                acc[0][r] *= corr;
                acc[1][r] *= corr;
            }
            mrun = mnew;
        }

#pragma unroll
        for (int r = 0; r < 16; ++r) {
            const float p = fast_exp2(s[r] - mrun);
            s[r] = p;
            lsum += p;
        }

        // ---- P pack (B-operand), slot e -> k-pattern (e&3)+8(e>>2)+4hi ----
        bf16x8 pb0, pb1;
#pragma unroll
        for (int e = 0; e < 8; ++e) { pb0[e] = (__bf16)s[e]; pb1[e] = (__bf16)s[8 + e]; }

        // ---- PV transposed: acc[dt] = mfma(V^T frag, P frag) ----
        __builtin_amdgcn_s_setprio(1);
        acc[0] = __builtin_amdgcn_mfma_f32_32x32x16_bf16(vcur[0], pb0, acc[0], 0, 0, 0);
        acc[1] = __builtin_amdgcn_mfma_f32_32x32x16_bf16(vcur[1], pb0, acc[1], 0, 0, 0);
        acc[0] = __builtin_amdgcn_mfma_f32_32x32x16_bf16(vcur[2], pb1, acc[0], 0, 0, 0);
        acc[1] = __builtin_amdgcn_mfma_f32_32x32x16_bf16(vcur[3], pb1, acc[1], 0, 0, 0);
        __builtin_amdgcn_s_setprio(0);

#pragma unroll
        for (int d4 = 0; d4 < 4; ++d4) kcur[d4] = knxt[d4];
    }

    // full row-sum (mrun already uniform across hi halves)
    lsum += __shfl_xor(lsum, 32);

    // ---- cascade merge 8 -> 4 -> 2 -> 1 (in-lane math; 4 barriers) ----
    auto write_slot = [&](int sl) {
        if (lane < 32) { lms[sl*32 + l31] = mrun; lls[sl*32 + l31] = lsum; }
        float* pp = lpart + sl*2176 + l31*68;
#pragma unroll
        for (int dt = 0; dt < 2; ++dt)
#pragma unroll
            for (int j = 0; j < 4; ++j) {
                f32x4 v;
#pragma unroll
                for (int c = 0; c < 4; ++c) v[c] = acc[dt][4*j + c];
                *reinterpret_cast<f32x4*>(pp + dt*32 + 8*j + 4*hi) = v;
            }
    };
    auto merge_slot = [&](int sl) {
        const float mp = lms[sl*32 + l31];
        const float lp = lls[sl*32 + l31];
        const float M  = fmaxf(mrun, mp);
        const float fo = fast_exp2(mrun - M);
        const float fp = fast_exp2(mp - M);
        lsum = lsum*fo + lp*fp;
        mrun = M;
        const float* pp = lpart + sl*2176 + l31*68;
#pragma unroll
        for (int dt = 0; dt < 2; ++dt)
#pragma unroll
            for (int j = 0; j < 4; ++j) {
                f32x4 v = *reinterpret_cast<const f32x4*>(pp + dt*32 + 8*j + 4*hi);
#pragma unroll
                for (int c = 0; c < 4; ++c)
                    acc[dt][4*j + c] = acc[dt][4*j + c]*fo + v[c]*fp;
            }
    };

    if (w >= 4) write_slot(w - 4);
    __syncthreads();
    if (w < 4) merge_slot(w);
    if (w == 2 || w == 3) write_slot(w);
    __syncthreads();
    if (w < 2) merge_slot(w + 2);
    if (w == 1) write_slot(1);
    __syncthreads();
    if (w == 0) {
        merge_slot(1);
        const float inv = 1.f / lsum;
#pragma unroll
        for (int dt = 0; dt < 2; ++dt)
#pragma unroll
            for (int r = 0; r < 16; ++r) acc[dt][r] *= inv;
        write_slot(0);   // final normalized result -> slot 0 (stats unused)
    }
    __syncthreads();

    // cooperative coalesced store: thread t -> q = t>>4, d-quad = (t&15)*4
    {
        const int q  = tid >> 4;
        const int dq = (tid & 15) * 4;
        f32x4 o = *reinterpret_cast<const f32x4*>(lpart + q*68 + dq);
        *reinterpret_cast<f32x4*>(out + ((long)b * SEQ + qbase + q) * DIM + dq) = o;
    }
}

// ---------------------------------------------------------------------------
extern "C" void kernel_launch(void* const* d_in, const int* in_sizes, int n_in,
                              void* d_out, int out_size, void* d_ws, size_t ws_size,
                              hipStream_t stream)
{
    const float* x = (const float*)d_in[0];
    const float* w = (const float*)d_in[1];
    float* out = (float*)d_out;

    char* ws = (char*)d_ws;
    const size_t sz = (size_t)NB * SEQ * DIM * sizeof(__bf16);  // 2 MiB each
    __bf16* Qf  = (__bf16*)(ws);                        // frag-major Q
    __bf16* Kf  = (__bf16*)(ws + sz);                   // frag-major K
    __bf16* Vf  = (__bf16*)(ws + 2 * sz);               // frag-major V
    __bf16* WT  = (__bf16*)(ws + 3 * sz);               // 24 KiB
    float*  peb = (float*)(ws + 3 * sz + 32 * 1024);    // 1 MiB

    const_prep_kernel<<<SEQ * DIM / 256, 256, 0, stream>>>(w, WT, peb);

    qkv_prep_kernel<<<NB * SEQ / 64, 256, 0, stream>>>(x, WT, peb, Qf, Kf, Vf);

    attn_kernel<<<NB * SEQ / 32, 512, 0, stream>>>(Qf, Kf, Vf, out);
}